// Round 5
// baseline (704.252 us; speedup 1.0000x reference)
//
#include <hip/hip_runtime.h>

// ES gradient for 2-layer MLP (D_IN=1024, HID=2048, D_OUT=10, POP=40, STD=0.1).
// k_xsplit (x -> LDS-ready split-f16 tiles) -> k_baseM (split-f16 MFMA x@W1+b1)
// -> k_big (split-f16 MFMA x@E1 + fused layer-2 partials) -> k_loss -> k_rank
// -> k_grad.  Losses only matter through RANKS (gaps ~1e-2); split-f16 GEMM err
// ~1e-5, pp-f16 err ~6e-4 => rank-exact.

#define NPLL 2119690LL          // N_PARAMS
#define S1_  2097152            // W1 end
#define S2_  2099200            // b1 end
#define S3_  2119680            // W2 end

// ws layout (f32 units):
//   base : [0, 524288)            base[j][b]  f32
//   ppu  : [524288, 2162688)      f16-packed [40][2][16][256][5dw]  (6.55 MB)
//   loss : [2162688, 2162768)
//   g    : [2162768, 2162808)
//   xs   : [2162816, +262144)     f16 [32 kt][256 b][64 c] (hi c0..31, lo c32..63)
#define WS_PP   524288
#define WS_LOSS 2162688
#define WS_G    2162768
#define WS_XS   2162816

typedef _Float16 f16;
typedef __fp16   fp16x2 __attribute__((ext_vector_type(2)));
typedef _Float16 f16x8 __attribute__((ext_vector_type(8)));
typedef float    f32x4 __attribute__((ext_vector_type(4)));

__device__ __forceinline__ unsigned pk2r(float a, float b, float& ra, float& rb) {
  fp16x2 h = __builtin_amdgcn_cvt_pkrtz(a, b);   // v_cvt_pkrtz_f16_f32
  ra = a - (float)h[0];
  rb = b - (float)h[1];
  return __builtin_bit_cast(unsigned, h);
}
__device__ __forceinline__ unsigned pk2(float a, float b) {
  fp16x2 h = __builtin_amdgcn_cvt_pkrtz(a, b);
  return __builtin_bit_cast(unsigned, h);
}
__device__ __forceinline__ unsigned packh(float a, float b) {  // RTN pack
  union { f16 h[2]; unsigned u; } v;
  v.h[0] = (f16)a; v.h[1] = (f16)b;
  return v.u;
}

// ---------------- k_xsplit: x (f32) -> xs[kt][b][64] split-f16 tiles --------
__global__ __launch_bounds__(256) void k_xsplit(const float* __restrict__ x,
                                                f16* __restrict__ xs) {
  const int idx = blockIdx.x * 256 + threadIdx.x;  // 32768 threads
  const int b  = idx >> 7;
  const int k8 = (idx & 127) * 8;
  const int kt = k8 >> 5, c = k8 & 31;
  float4 a0 = *(const float4*)&x[(size_t)b * 1024 + k8];
  float4 a1 = *(const float4*)&x[(size_t)b * 1024 + k8 + 4];
  float v[8] = {a0.x, a0.y, a0.z, a0.w, a1.x, a1.y, a1.z, a1.w};
  float r[8];
  uint4 H, L;
  H.x = pk2r(v[0], v[1], r[0], r[1]);
  H.y = pk2r(v[2], v[3], r[2], r[3]);
  H.z = pk2r(v[4], v[5], r[4], r[5]);
  H.w = pk2r(v[6], v[7], r[6], r[7]);
  L.x = pk2(r[0], r[1]); L.y = pk2(r[2], r[3]);
  L.z = pk2(r[4], r[5]); L.w = pk2(r[6], r[7]);
  f16* dst = &xs[((size_t)kt * 256 + b) * 64 + c];
  *(uint4*)dst = H;
  *(uint4*)(dst + 32) = L;
}

// ===== shared staging conventions for the two MFMA kernels =====
// LDS tiles: eA[j 128][ESTR], xB[b 128][ESTR]; cols 0..31 hi(k), 32..63 lo(k).
// A-frag (row j): lane lm=lane&15 -> row, g8=(lane>>4)*8 -> k-chunk.
// D layout: row j = (lane>>4)*4 + reg, col b = lane&15.
#define ESTR 72

// ---------------- k_baseM: base[j][b] = (x @ W1)[b][j] + b1[j] --------------
// grid (16 jt, 2 bt), 256 threads = 4 waves (2jw x 2bw), wave 64j x 64b.
__global__ __launch_bounds__(256, 3) void k_baseM(const f16* __restrict__ xs,
                                                  const float* __restrict__ W1,
                                                  const float* __restrict__ b1,
                                                  float* __restrict__ base) {
  __shared__ __align__(16) f16 eA[128 * ESTR];
  __shared__ __align__(16) f16 xB[128 * ESTR];
  const int t = threadIdx.x;
  const int jt = blockIdx.x, bt = blockIdx.y;
  const int j0 = jt * 128, b0 = bt * 128;
  const int wave = t >> 6, lane = t & 63;
  const int lm = lane & 15, g8 = (lane >> 4) * 8, g4 = (lane >> 4) * 4;
  const int jw = (wave & 1) * 64, bw = (wave >> 1) * 64;
  const int rl = t & 127, kgrp = (t >> 7) * 16;

  float ve[16];
  uint4 vx[4];
  f32x4 acc[4][4];
#pragma unroll
  for (int a = 0; a < 4; ++a)
#pragma unroll
    for (int b = 0; b < 4; ++b) acc[a][b] = (f32x4){0.f, 0.f, 0.f, 0.f};

#define LOADE_W(K0)                                                            \
  do {                                                                         \
    const float* eg = &W1[(size_t)((K0) + kgrp) * 2048 + j0 + rl];             \
    _Pragma("unroll") for (int d = 0; d < 16; ++d) ve[d] = eg[(size_t)d * 2048];\
  } while (0)
#define LOADX_(K0)                                                             \
  do {                                                                         \
    const f16* xg = &xs[((size_t)(((K0) >> 5) * 256 + b0)) * 64];              \
    _Pragma("unroll") for (int q = 0; q < 4; ++q) {                            \
      int ci = q * 256 + t;                                                    \
      vx[q] = *(const uint4*)&xg[(ci >> 3) * 64 + (ci & 7) * 8];               \
    }                                                                          \
  } while (0)
#define CVTE()                                                                 \
  do {                                                                         \
    float r[16];                                                               \
    uint4 H0, H1, L0, L1;                                                      \
    H0.x = pk2r(ve[0], ve[1], r[0], r[1]);                                     \
    H0.y = pk2r(ve[2], ve[3], r[2], r[3]);                                     \
    H0.z = pk2r(ve[4], ve[5], r[4], r[5]);                                     \
    H0.w = pk2r(ve[6], ve[7], r[6], r[7]);                                     \
    H1.x = pk2r(ve[8], ve[9], r[8], r[9]);                                     \
    H1.y = pk2r(ve[10], ve[11], r[10], r[11]);                                 \
    H1.z = pk2r(ve[12], ve[13], r[12], r[13]);                                 \
    H1.w = pk2r(ve[14], ve[15], r[14], r[15]);                                 \
    *(uint4*)&eA[rl * ESTR + kgrp] = H0;                                       \
    *(uint4*)&eA[rl * ESTR + kgrp + 8] = H1;                                   \
    L0.x = pk2(r[0], r[1]);  L0.y = pk2(r[2], r[3]);                           \
    L0.z = pk2(r[4], r[5]);  L0.w = pk2(r[6], r[7]);                           \
    L1.x = pk2(r[8], r[9]);  L1.y = pk2(r[10], r[11]);                         \
    L1.z = pk2(r[12], r[13]); L1.w = pk2(r[14], r[15]);                        \
    *(uint4*)&eA[rl * ESTR + 32 + kgrp] = L0;                                  \
    *(uint4*)&eA[rl * ESTR + 32 + kgrp + 8] = L1;                              \
  } while (0)
#define WRX()                                                                  \
  _Pragma("unroll") for (int q = 0; q < 4; ++q) {                              \
    int ci = q * 256 + t;                                                      \
    *(uint4*)&xB[(ci >> 3) * ESTR + (ci & 7) * 8] = vx[q];                     \
  }
#define KSTEP_BODY(LOADE_NEXT)                                                 \
  __syncthreads();                                                             \
  CVTE();                                                                      \
  WRX();                                                                       \
  LOADE_NEXT;                                                                  \
  __syncthreads();                                                             \
  {                                                                            \
    f16x8 Bh[4], Bl[4];                                                        \
    _Pragma("unroll") for (int nf = 0; nf < 4; ++nf) {                         \
      Bh[nf] = *(const f16x8*)&xB[(bw + nf * 16 + lm) * ESTR + g8];            \
      Bl[nf] = *(const f16x8*)&xB[(bw + nf * 16 + lm) * ESTR + 32 + g8];       \
    }                                                                          \
    _Pragma("unroll") for (int mf = 0; mf < 4; ++mf) {                         \
      f16x8 Ah = *(const f16x8*)&eA[(jw + mf * 16 + lm) * ESTR + g8];          \
      f16x8 Al = *(const f16x8*)&eA[(jw + mf * 16 + lm) * ESTR + 32 + g8];     \
      _Pragma("unroll") for (int nf = 0; nf < 4; ++nf) {                       \
        acc[mf][nf] = __builtin_amdgcn_mfma_f32_16x16x32_f16(Ah, Bh[nf], acc[mf][nf], 0, 0, 0); \
        acc[mf][nf] = __builtin_amdgcn_mfma_f32_16x16x32_f16(Ah, Bl[nf], acc[mf][nf], 0, 0, 0); \
        acc[mf][nf] = __builtin_amdgcn_mfma_f32_16x16x32_f16(Al, Bh[nf], acc[mf][nf], 0, 0, 0); \
      }                                                                        \
    }                                                                          \
  }

  LOADE_W(0);
  LOADX_(0);
  for (int ks = 0; ks < 32; ++ks) {
    const int kn = (ks + 1) * 32;
    KSTEP_BODY(if (ks < 31) { LOADE_W(kn); LOADX_(kn); });
  }

#pragma unroll
  for (int mf = 0; mf < 4; ++mf)
#pragma unroll
    for (int r = 0; r < 4; ++r) {
      const int jl = jw + mf * 16 + g4 + r;
      const float bv = b1[j0 + jl];
#pragma unroll
      for (int nf = 0; nf < 4; ++nf) {
        const int bl = bw + nf * 16 + lm;
        base[(size_t)(j0 + jl) * 256 + b0 + bl] = acc[mf][nf][r] + bv;
      }
    }
}

// ---------------- k_big: split-f16 MFMA x@E1 + fused epilogue ---------------
// grid (40 p, 16 jt, 2 bt), 256 threads = 4 waves, wave 64j x 64b.
__global__ __launch_bounds__(256, 3) void k_big(const f16* __restrict__ xs,
                                                const float* __restrict__ noise,
                                                const float* __restrict__ W2,
                                                const float* __restrict__ base,
                                                unsigned* __restrict__ ppu) {
  __shared__ __align__(16) f16 eA[128 * ESTR];
  __shared__ __align__(16) f16 xB[128 * ESTR];
  __shared__ float w2l[1280], e2l[1280], e1l[128];
  __shared__ float red[1280];

  const int t = threadIdx.x;
  const int p = blockIdx.x, jt = blockIdx.y, bt = blockIdx.z;
  const int j0 = jt * 128, b0 = bt * 128;
  const int wave = t >> 6, lane = t & 63;
  const int lm = lane & 15, g8 = (lane >> 4) * 8, g4 = (lane >> 4) * 4;
  const int jw = (wave & 1) * 64, bw = (wave >> 1) * 64;
  const size_t pN = (size_t)p * NPLL;
  const int rl = t & 127, kgrp = (t >> 7) * 16;

  // epilogue tables (visibility guaranteed by k-loop barriers)
  for (int i = t; i < 1280; i += 256) {
    w2l[i] = W2[j0 * 10 + i];
    e2l[i] = noise[pN + S2_ + (size_t)j0 * 10 + i];
  }
  if (t < 128) e1l[t] = noise[pN + S1_ + j0 + t];

  float ve[16];
  uint4 vx[4];
  f32x4 acc[4][4];
#pragma unroll
  for (int a = 0; a < 4; ++a)
#pragma unroll
    for (int b = 0; b < 4; ++b) acc[a][b] = (f32x4){0.f, 0.f, 0.f, 0.f};

#define LOADE_N(K0)                                                            \
  do {                                                                         \
    const float* eg = &noise[pN + (size_t)((K0) + kgrp) * 2048 + j0 + rl];     \
    _Pragma("unroll") for (int d = 0; d < 16; ++d) ve[d] = eg[(size_t)d * 2048];\
  } while (0)

  LOADE_N(0);
  LOADX_(0);
  for (int ks = 0; ks < 32; ++ks) {
    const int kn = (ks + 1) * 32;
    KSTEP_BODY(if (ks < 31) { LOADE_N(kn); LOADX_(kn); });
  }

  // ---- epilogue: one sign at a time ----
#pragma unroll 1
  for (int s = 0; s < 2; ++s) {
    const float sf = s ? -0.1f : 0.1f;
    float ppv[4][10];
#pragma unroll
    for (int nf = 0; nf < 4; ++nf)
#pragma unroll
      for (int o = 0; o < 10; ++o) ppv[nf][o] = 0.f;
#pragma unroll
    for (int mf = 0; mf < 4; ++mf)
#pragma unroll
      for (int r = 0; r < 4; ++r) {
        const int jl = jw + mf * 16 + g4 + r;
        const float e1v = e1l[jl];
        float w2s[10];
#pragma unroll
        for (int o = 0; o < 10; ++o)
          w2s[o] = fmaf(sf, e2l[jl * 10 + o], w2l[jl * 10 + o]);
#pragma unroll
        for (int nf = 0; nf < 4; ++nf) {
          const int bl = bw + nf * 16 + lm;
          const float bs = base[(size_t)(j0 + jl) * 256 + b0 + bl];
          const float h = fmaxf(fmaf(sf, acc[mf][nf][r] + e1v, bs), 0.f);
#pragma unroll
          for (int o = 0; o < 10; ++o) ppv[nf][o] = fmaf(h, w2s[o], ppv[nf][o]);
        }
      }
#pragma unroll
    for (int nf = 0; nf < 4; ++nf)
#pragma unroll
      for (int o = 0; o < 10; ++o) {
        float v = ppv[nf][o];
        v += __shfl_xor(v, 16, 64);
        v += __shfl_xor(v, 32, 64);
        ppv[nf][o] = v;
      }
    __syncthreads();
    if ((wave & 1) == 1 && lane < 16) {
#pragma unroll
      for (int nf = 0; nf < 4; ++nf)
#pragma unroll
        for (int o = 0; o < 10; ++o)
          red[(bw + nf * 16 + lm) * 10 + o] = ppv[nf][o];
    }
    __syncthreads();
    if ((wave & 1) == 0 && lane < 16) {
#pragma unroll
      for (int nf = 0; nf < 4; ++nf) {
        const int bl = bw + nf * 16 + lm;
        float f[10];
#pragma unroll
        for (int o = 0; o < 10; ++o) f[o] = ppv[nf][o] + red[bl * 10 + o];
        const size_t u0 = ((((size_t)p * 2 + s) * 16 + jt) * 256 + b0 + bl) * 5;
        ppu[u0 + 0] = packh(f[0], f[1]);
        ppu[u0 + 1] = packh(f[2], f[3]);
        ppu[u0 + 2] = packh(f[4], f[5]);
        ppu[u0 + 3] = packh(f[6], f[7]);
        ppu[u0 + 4] = packh(f[8], f[9]);
      }
    }
  }
}

// ---------------- k_loss: 80 losses ----------------
__global__ __launch_bounds__(256) void k_loss(const unsigned* __restrict__ ppu,
                                              const float* __restrict__ y,
                                              const float* __restrict__ b2,
                                              const float* __restrict__ noise,
                                              float* __restrict__ loss) {
  const int b = threadIdx.x;
  const int p = blockIdx.x >> 1, s = blockIdx.x & 1;
  const float sf = s ? -0.1f : 0.1f;
  const size_t pN = (size_t)p * NPLL;
  float pred[10];
#pragma unroll
  for (int o = 0; o < 10; ++o) pred[o] = b2[o] + sf * noise[pN + S3_ + o];
  for (int jt = 0; jt < 16; ++jt) {
    const size_t u0 = ((((size_t)p * 2 + s) * 16 + jt) * 256 + b) * 5;
#pragma unroll
    for (int q = 0; q < 5; ++q) {
      union { unsigned u; f16 h[2]; } w;
      w.u = ppu[u0 + q];
      pred[2 * q]     += (float)w.h[0];
      pred[2 * q + 1] += (float)w.h[1];
    }
  }
  float e = 0.f;
#pragma unroll
  for (int o = 0; o < 10; ++o) {
    float d = pred[o] - y[b * 10 + o];
    e += d * d;
  }
  __shared__ float red[256];
  red[b] = e;
  __syncthreads();
  for (int st = 128; st > 0; st >>= 1) {
    if (b < st) red[b] += red[b + st];
    __syncthreads();
  }
  if (b == 0) loss[blockIdx.x] = red[0] * (1.0f / 2560.0f);
}

// ---------------- k_rank: stable centered ranks -> pair coefficients --------
__global__ void k_rank(const float* __restrict__ loss, float* __restrict__ g) {
  __shared__ float ls[80];
  __shared__ float rk[80];
  const int t = threadIdx.x;
  if (t < 80) ls[t] = loss[t];
  __syncthreads();
  if (t < 80) {
    float li = ls[t];
    int r = 0;
    for (int j = 0; j < 80; ++j) {
      float lj = ls[j];
      r += (lj < li) || (lj == li && j < t);  // stable tie-break = argsort
    }
    rk[t] = (float)r;
  }
  __syncthreads();
  if (t < 40) g[t] = (rk[2 * t] - rk[2 * t + 1]) * (1.0f / (79.0f * 40.0f));
}

// ---------------- k_grad: out[k] = sum_p noise[p][k] * g[p] -----------------
__global__ __launch_bounds__(256) void k_grad(const float* __restrict__ noise,
                                              const float* __restrict__ g,
                                              float* __restrict__ out) {
  __shared__ float gg[40];
  const int t = threadIdx.x;
  if (t < 40) gg[t] = g[t];
  __syncthreads();
  const long long NH = NPLL / 2;
  long long idx = (long long)blockIdx.x * 256 + t;
  if (idx >= NH) return;
  float2 a = make_float2(0.f, 0.f);
#pragma unroll 8
  for (int p = 0; p < 40; ++p) {
    float2 v = *(const float2*)&noise[(size_t)p * NPLL + idx * 2];
    a.x += v.x * gg[p];
    a.y += v.y * gg[p];
  }
  *(float2*)&out[idx * 2] = a;
}

extern "C" void kernel_launch(void* const* d_in, const int* in_sizes, int n_in,
                              void* d_out, int out_size, void* d_ws, size_t ws_size,
                              hipStream_t stream) {
  const float* x     = (const float*)d_in[0];
  const float* y     = (const float*)d_in[1];
  const float* W1    = (const float*)d_in[2];
  const float* b1    = (const float*)d_in[3];
  const float* W2    = (const float*)d_in[4];
  const float* b2    = (const float*)d_in[5];
  const float* noise = (const float*)d_in[6];
  float* out  = (float*)d_out;
  float* ws   = (float*)d_ws;   // ~9.7 MB used
  float* base = ws;
  unsigned* ppu = (unsigned*)(ws + WS_PP);
  float* loss = ws + WS_LOSS;
  float* g    = ws + WS_G;
  f16* xs = (f16*)(ws + WS_XS);

  k_xsplit<<<128, 256, 0, stream>>>(x, xs);
  k_baseM<<<dim3(16, 2), 256, 0, stream>>>(xs, W1, b1, base);
  k_big<<<dim3(40, 16, 2), 256, 0, stream>>>(xs, noise, W2, base, ppu);
  k_loss<<<80, 256, 0, stream>>>(ppu, y, b2, noise, loss);
  k_rank<<<1, 128, 0, stream>>>(loss, g);
  k_grad<<<4141, 256, 0, stream>>>(noise, g, out);
}